// Round 11
// baseline (269.291 us; speedup 1.0000x reference)
//
#include <hip/hip_runtime.h>

#define NN 50000
#define NE 800000
#define NB 782        // buckets of 64 nodes
#define NBLK 256      // p12 blocks
#define CHUNK 3125    // NBLK * CHUNK == NE exactly
#define CAP 1536      // per-bucket slot cap (mean 1024)
#define CAPTOT (NB * CAP)

// bf16 helpers (raw ushort storage, fp32 math)
__device__ __forceinline__ float blo(unsigned u) { return __uint_as_float(u << 16); }
__device__ __forceinline__ float bhi(unsigned u) { return __uint_as_float(u & 0xFFFF0000u); }
__device__ __forceinline__ unsigned short f2b(float f) {   // round-to-nearest-even
    unsigned u = __float_as_uint(f);
    return (unsigned short)((u + 0x7FFFu + ((u >> 16) & 1u)) >> 16);
}

// ---- init: fixed-stride bucket cursors ----
__global__ void k_init(int* __restrict__ cursor) {
    int i = blockIdx.x * blockDim.x + threadIdx.x;
    if (i < NB) cursor[i] = i * CAP;
}

// ---- single-pass bucket scatter: LDS-stage chunk, LDS hist, global reserve, scatter ----
__global__ __launch_bounds__(256) void p12(const int* __restrict__ src,
        const int* __restrict__ dst, const float* __restrict__ w,
        int* __restrict__ cursor, int2* __restrict__ stage) {
    __shared__ unsigned se[CHUNK];
    __shared__ float    sw[CHUNK];
    __shared__ int      lh[NB];
    int t = threadIdx.x;
    for (int i = t; i < NB; i += 256) lh[i] = 0;
    __syncthreads();
    int e0 = blockIdx.x * CHUNK;
    for (int i = t; i < CHUNK; i += 256) {
        int e = e0 + i;
        unsigned d = (unsigned)dst[e];
        unsigned s = (unsigned)src[e];
        float wv = w[e];
        unsigned pk = 0xFFFFFFFFu;   // invalid marker
        if (d < NN) {
            pk = (s & 0xFFFFu) | ((d & 63u) << 16) | ((d >> 6) << 22);
            atomicAdd(&lh[d >> 6], 1);
        }
        se[i] = pk;
        sw[i] = wv;
    }
    __syncthreads();
    for (int i = t; i < NB; i += 256) {
        int c = lh[i];
        lh[i] = c ? atomicAdd(&cursor[i], c) : 0;   // lh becomes global write cursor
    }
    __syncthreads();
    for (int i = t; i < CHUNK; i += 256) {
        unsigned pk = se[i];
        if (pk != 0xFFFFFFFFu) {
            int bucket = (int)(pk >> 22);
            int pos = atomicAdd(&lh[bucket], 1);    // LDS atomic
            if (pos < (bucket + 1) * CAP)
                stage[pos] = make_int2((int)(pk & 0x3FFFFFu), __float_as_int(sw[i]));
        }
    }
}

// ---- per-bucket row sort: stage -> compact 4B csr (src16 | w-bf16); row_ptr/deg/dinv ----
__global__ __launch_bounds__(256) void p3_sort(const int2* __restrict__ stage,
        const int* __restrict__ cursor, unsigned* __restrict__ csr4,
        int* __restrict__ row_ptr, int* __restrict__ row_deg, float* __restrict__ dinv) {
    __shared__ int   hist[64];
    __shared__ int   cur[64];
    __shared__ float wsum[64];
    int b = blockIdx.x, t = threadIdx.x;
    int g0 = b * CAP;
    int g1 = cursor[b];
    int gmax = g0 + CAP;
    if (g1 > gmax) g1 = gmax;
    if (t < 64) { hist[t] = 0; wsum[t] = 0.f; }
    __syncthreads();
    for (int j = g0 + t; j < g1; j += 256) {
        int2 pk = stage[j];
        int r = (pk.x >> 16) & 63;
        atomicAdd(&hist[r], 1);
        atomicAdd(&wsum[r], __int_as_float(pk.y));   // fused weighted degree (fp32)
    }
    __syncthreads();
    if (t == 0) {
        int s = g0;
        for (int r = 0; r < 64; ++r) { cur[r] = s; s += hist[r]; }
    }
    __syncthreads();
    if (t < 64) {
        int n = b * 64 + t;
        if (n < NN) {
            row_ptr[n] = cur[t];
            row_deg[n] = hist[t];
            dinv[n] = rsqrtf(wsum[t] + 1.0f);
        }
    }
    __syncthreads();
    for (int j = g0 + t; j < g1; j += 256) {
        int2 pk = stage[j];
        int r = (pk.x >> 16) & 63;
        int pos = atomicAdd(&cur[r], 1);
        csr4[pos] = (unsigned)(pk.x & 0xFFFF) |
                    ((unsigned)f2b(__int_as_float(pk.y)) << 16);
    }
}

// hp slice-major: plane s holds feats [8s,8s+8) of all nodes; ushort idx (s*NN+n)*8+(f&7)
// ---- layer-0 GEMM: x fp32 row-major -> hp_sm bf16, dinv prescale ----
__global__ __launch_bounds__(256) void gemm0_kernel(const float* __restrict__ x,
        const float* __restrict__ W, const float* __restrict__ dinv,
        unsigned short* __restrict__ hp) {
    __shared__ float xs[16][64];
    int t = threadIdx.x;
    int base = blockIdx.x * 16;
    for (int idx = t; idx < 16 * 64; idx += 256)
        xs[idx >> 6][idx & 63] = x[(size_t)(base + (idx >> 6)) * 64 + (idx & 63)];
    __syncthreads();
    int col = t & 63, rq = t >> 6;
    float wc[64];
#pragma unroll
    for (int k = 0; k < 64; ++k) wc[k] = W[k * 64 + col];
    float a0 = 0.f, a1 = 0.f, a2 = 0.f, a3 = 0.f;
#pragma unroll
    for (int k = 0; k < 64; ++k) {
        float wk = wc[k];
        a0 += xs[rq     ][k] * wk;
        a1 += xs[rq +  4][k] * wk;
        a2 += xs[rq +  8][k] * wk;
        a3 += xs[rq + 12][k] * wk;
    }
    int r = base + rq;
    size_t pbase = (size_t)(col >> 3) * NN * 8 + (col & 7);
    hp[pbase + (size_t)(r     ) * 8] = f2b(dinv[r     ] * a0);
    hp[pbase + (size_t)(r +  4) * 8] = f2b(dinv[r +  4] * a1);
    hp[pbase + (size_t)(r +  8) * 8] = f2b(dinv[r +  8] * a2);
    hp[pbase + (size_t)(r + 12) * 8] = f2b(dinv[r + 12] * a3);
}

// ---- layers 1,2 GEMM: y bf16 slice-major -> hp_sm bf16, dinv prescale ----
__global__ __launch_bounds__(256) void gemmn_kernel(const unsigned short* __restrict__ y,
        const float* __restrict__ W, const float* __restrict__ dinv,
        unsigned short* __restrict__ hp) {
    __shared__ float xs[16][64];
    int t = threadIdx.x;
    int base = blockIdx.x * 16;
    for (int idx = t; idx < 16 * 64; idx += 256) {
        int node = base + (idx >> 6), f = idx & 63;
        xs[idx >> 6][f] = blo((unsigned)y[(size_t)(f >> 3) * NN * 8 + (size_t)node * 8 + (f & 7)]);
    }
    __syncthreads();
    int col = t & 63, rq = t >> 6;
    float wc[64];
#pragma unroll
    for (int k = 0; k < 64; ++k) wc[k] = W[k * 64 + col];
    float a0 = 0.f, a1 = 0.f, a2 = 0.f, a3 = 0.f;
#pragma unroll
    for (int k = 0; k < 64; ++k) {
        float wk = wc[k];
        a0 += xs[rq     ][k] * wk;
        a1 += xs[rq +  4][k] * wk;
        a2 += xs[rq +  8][k] * wk;
        a3 += xs[rq + 12][k] * wk;
    }
    int r = base + rq;
    size_t pbase = (size_t)(col >> 3) * NN * 8 + (col & 7);
    hp[pbase + (size_t)(r     ) * 8] = f2b(dinv[r     ] * a0);
    hp[pbase + (size_t)(r +  4) * 8] = f2b(dinv[r +  4] * a1);
    hp[pbase + (size_t)(r +  8) * 8] = f2b(dinv[r +  8] * a2);
    hp[pbase + (size_t)(r + 12) * 8] = f2b(dinv[r + 12] * a3);
}

// sliced gather core: 4-lane group per node, slice = 8 feats (4 uints of bf16 pairs).
// slice = blockIdx % 8 -> XCD round-robin pins each 800 KB hp plane in one XCD's L2.
__device__ __forceinline__ float2 gather_body(int n, int gl, int gbase,
        const int* __restrict__ row_ptr, const int* __restrict__ row_deg,
        const unsigned* __restrict__ csr4, const unsigned* __restrict__ hps) {
    int s0 = row_ptr[n], cnt = row_deg[n];
    unsigned self = hps[n * 4 + gl];
    float ax = blo(self), ay = bhi(self);
    float bx = 0.f, by = 0.f;
    int base = 0;
    for (; base + 4 <= cnt; base += 4) {
        unsigned meta = csr4[s0 + base + gl];
        unsigned m0 = __shfl(meta, gbase + 0);
        unsigned m1 = __shfl(meta, gbase + 1);
        unsigned m2 = __shfl(meta, gbase + 2);
        unsigned m3 = __shfl(meta, gbase + 3);
        unsigned u0 = hps[(m0 & 0xFFFFu) * 4 + gl];
        unsigned u1 = hps[(m1 & 0xFFFFu) * 4 + gl];
        unsigned u2 = hps[(m2 & 0xFFFFu) * 4 + gl];
        unsigned u3 = hps[(m3 & 0xFFFFu) * 4 + gl];
        float w0 = __uint_as_float(m0 & 0xFFFF0000u);
        float w1 = __uint_as_float(m1 & 0xFFFF0000u);
        float w2 = __uint_as_float(m2 & 0xFFFF0000u);
        float w3 = __uint_as_float(m3 & 0xFFFF0000u);
        ax += w0 * blo(u0); ay += w0 * bhi(u0);
        bx += w1 * blo(u1); by += w1 * bhi(u1);
        ax += w2 * blo(u2); ay += w2 * bhi(u2);
        bx += w3 * blo(u3); by += w3 * bhi(u3);
    }
    int rem = cnt - base;
    if (rem > 0) {
        unsigned meta = (gl < rem) ? csr4[s0 + base + gl] : 0u;
        for (int jj = 0; jj < rem; ++jj) {
            unsigned mm = __shfl(meta, gbase + jj);
            unsigned u = hps[(mm & 0xFFFFu) * 4 + gl];
            float w = __uint_as_float(mm & 0xFFFF0000u);
            ax += w * blo(u); ay += w * bhi(u);
        }
    }
    return make_float2(ax + bx, ay + by);
}

// mid layers: gather -> bias+relu -> y bf16 slice-major (coalesced uint store)
__global__ __launch_bounds__(256) void gather_mid(const int* __restrict__ row_ptr,
        const int* __restrict__ row_deg, const unsigned* __restrict__ csr4,
        const float* __restrict__ dinv, const unsigned* __restrict__ hp,
        const float* __restrict__ bias, unsigned* __restrict__ y) {
    int t = threadIdx.x;
    int s = blockIdx.x & 7;
    int nb = blockIdx.x >> 3;
    int lane = t & 63;
    int g = lane >> 2, gl = lane & 3;
    int n = nb * 64 + ((t >> 6) << 4) + g;
    if (n >= NN) return;
    const unsigned* hps = hp + (size_t)s * NN * 4;
    float2 acc = gather_body(n, gl, g << 2, row_ptr, row_deg, csr4, hps);
    float dv = dinv[n];
    float2 bb = ((const float2*)bias)[s * 4 + gl];
    float rx = fmaxf(dv * acc.x + bb.x, 0.f);
    float ry = fmaxf(dv * acc.y + bb.y, 0.f);
    y[(size_t)s * NN * 4 + (size_t)n * 4 + gl] =
        (unsigned)f2b(rx) | ((unsigned)f2b(ry) << 16);
}

// final layer: gather -> bias+relu -> fp32 out (row-major)
__global__ __launch_bounds__(256) void gather_final(const int* __restrict__ row_ptr,
        const int* __restrict__ row_deg, const unsigned* __restrict__ csr4,
        const float* __restrict__ dinv, const unsigned* __restrict__ hp,
        const float* __restrict__ bias, float* __restrict__ out) {
    int t = threadIdx.x;
    int s = blockIdx.x & 7;
    int nb = blockIdx.x >> 3;
    int lane = t & 63;
    int g = lane >> 2, gl = lane & 3;
    int n = nb * 64 + ((t >> 6) << 4) + g;
    if (n >= NN) return;
    const unsigned* hps = hp + (size_t)s * NN * 4;
    float2 acc = gather_body(n, gl, g << 2, row_ptr, row_deg, csr4, hps);
    float dv = dinv[n];
    float2 bb = ((const float2*)bias)[s * 4 + gl];
    float2 r;
    r.x = fmaxf(dv * acc.x + bb.x, 0.f);
    r.y = fmaxf(dv * acc.y + bb.y, 0.f);
    ((float2*)out)[(size_t)n * 32 + s * 4 + gl] = r;
}

extern "C" void kernel_launch(void* const* d_in, const int* in_sizes, int n_in,
                              void* d_out, int out_size, void* d_ws, size_t ws_size,
                              hipStream_t stream) {
    const float* x  = (const float*)d_in[0];
    const int*   ei = (const int*)d_in[1];    // int32 [2, NE] flat
    const float* ew = (const float*)d_in[2];
    const float* W0 = (const float*)d_in[3];
    const float* b0 = (const float*)d_in[4];
    const float* W1 = (const float*)d_in[5];
    const float* b1 = (const float*)d_in[6];
    const float* W2 = (const float*)d_in[7];
    const float* b2 = (const float*)d_in[8];
    float*       out = (float*)d_out;

    const int* src = ei;
    const int* dst = ei + NE;

    // workspace layout, ~28 MB total
    int2*     stage   = (int2*)d_ws;                     // CAPTOT (9.6 MB)
    unsigned* csr4    = (unsigned*)(stage + CAPTOT);     // CAPTOT (4.8 MB)
    int*      cursor  = (int*)(csr4 + CAPTOT);           // NB
    int*      row_ptr = cursor + NB;                     // NN
    int*      row_deg = row_ptr + NN;                    // NN
    float*    dinv    = (float*)(row_deg + NN);          // NN
    unsigned short* hp = (unsigned short*)(dinv + NN);   // NN*64 bf16 slice-major (6.4 MB)
    unsigned short* y  = hp + (size_t)NN * 64;           // NN*64 bf16 slice-major (6.4 MB)

    // ---- CSR build (once, shared by all 3 layers) ----
    k_init<<<1, 1024, 0, stream>>>(cursor);
    p12<<<NBLK, 256, 0, stream>>>(src, dst, ew, cursor, stage);
    p3_sort<<<NB, 256, 0, stream>>>(stage, cursor, csr4, row_ptr, row_deg, dinv);

    // ---- layer 0 ----
    gemm0_kernel<<<NN / 16, 256, 0, stream>>>(x, W0, dinv, hp);
    gather_mid<<<NB * 8, 256, 0, stream>>>(row_ptr, row_deg, csr4, dinv,
            (const unsigned*)hp, b0, (unsigned*)y);
    // ---- layer 1 ----
    gemmn_kernel<<<NN / 16, 256, 0, stream>>>(y, W1, dinv, hp);
    gather_mid<<<NB * 8, 256, 0, stream>>>(row_ptr, row_deg, csr4, dinv,
            (const unsigned*)hp, b1, (unsigned*)y);
    // ---- layer 2 ----
    gemmn_kernel<<<NN / 16, 256, 0, stream>>>(y, W2, dinv, hp);
    gather_final<<<NB * 8, 256, 0, stream>>>(row_ptr, row_deg, csr4, dinv,
            (const unsigned*)hp, b2, out);
}

// Round 13
// 203.919 us; speedup vs baseline: 1.3206x; 1.3206x over previous
//
#include <hip/hip_runtime.h>

#define NN 50000
#define NE 800000
#define NB 782        // buckets of 64 nodes
#define NBLK 256      // p12 blocks
#define CHUNK 3125    // NBLK * CHUNK == NE exactly
#define CAP 1536      // per-bucket slot cap (mean 1024)
#define CAPTOT (NB * CAP)

typedef float f32x4 __attribute__((ext_vector_type(4)));   // native vector for nontemporal store

// bf16 helpers (raw ushort storage, fp32 math)
__device__ __forceinline__ float blo(unsigned u) { return __uint_as_float(u << 16); }
__device__ __forceinline__ float bhi(unsigned u) { return __uint_as_float(u & 0xFFFF0000u); }
__device__ __forceinline__ unsigned short f2b(float f) {   // round-to-nearest-even
    unsigned u = __float_as_uint(f);
    return (unsigned short)((u + 0x7FFFu + ((u >> 16) & 1u)) >> 16);
}

// ---- single-pass bucket scatter: LDS-stage chunk, LDS hist, global reserve, scatter ----
// cursor[] is zero-initialized (hipMemsetAsync); slots are bucket-relative.
__global__ __launch_bounds__(256) void p12(const int* __restrict__ src,
        const int* __restrict__ dst, const float* __restrict__ w,
        int* __restrict__ cursor, int2* __restrict__ stage) {
    __shared__ unsigned se[CHUNK];
    __shared__ float    sw[CHUNK];
    __shared__ int      lh[NB];
    int t = threadIdx.x;
    for (int i = t; i < NB; i += 256) lh[i] = 0;
    __syncthreads();
    int e0 = blockIdx.x * CHUNK;
    for (int i = t; i < CHUNK; i += 256) {
        int e = e0 + i;
        unsigned d = (unsigned)dst[e];
        unsigned s = (unsigned)src[e];
        float wv = w[e];
        unsigned pk = 0xFFFFFFFFu;   // invalid marker
        if (d < NN) {
            pk = (s & 0xFFFFu) | ((d & 63u) << 16) | ((d >> 6) << 22);
            atomicAdd(&lh[d >> 6], 1);
        }
        se[i] = pk;
        sw[i] = wv;
    }
    __syncthreads();
    for (int i = t; i < NB; i += 256) {
        int c = lh[i];
        lh[i] = c ? (i * CAP + atomicAdd(&cursor[i], c)) : 0;  // global write cursor
    }
    __syncthreads();
    for (int i = t; i < CHUNK; i += 256) {
        unsigned pk = se[i];
        if (pk != 0xFFFFFFFFu) {
            int bucket = (int)(pk >> 22);
            int pos = atomicAdd(&lh[bucket], 1);    // LDS atomic
            if (pos < (bucket + 1) * CAP)
                stage[pos] = make_int2((int)(pk & 0x3FFFFFu), __float_as_int(sw[i]));
        }
    }
}

// ---- per-bucket row sort: stage -> 4B csr (src16 | w-bf16); emit row_ptr/row_deg/dinv ----
__global__ __launch_bounds__(256) void p3_sort(const int2* __restrict__ stage,
        const int* __restrict__ cursor, unsigned* __restrict__ csr4,
        int* __restrict__ row_ptr, int* __restrict__ row_deg, float* __restrict__ dinv) {
    __shared__ int   hist[64];
    __shared__ int   cur[64];
    __shared__ float wsum[64];
    int b = blockIdx.x, t = threadIdx.x;
    int g0 = b * CAP;
    int cnt = cursor[b];
    if (cnt > CAP) cnt = CAP;
    int g1 = g0 + cnt;
    if (t < 64) { hist[t] = 0; wsum[t] = 0.f; }
    __syncthreads();
    for (int j = g0 + t; j < g1; j += 256) {
        int2 pk = stage[j];
        int r = (pk.x >> 16) & 63;
        atomicAdd(&hist[r], 1);
        atomicAdd(&wsum[r], __int_as_float(pk.y));   // fused weighted degree (fp32)
    }
    __syncthreads();
    if (t == 0) {
        int s = g0;
        for (int r = 0; r < 64; ++r) { cur[r] = s; s += hist[r]; }
    }
    __syncthreads();
    if (t < 64) {
        int n = b * 64 + t;
        if (n < NN) {
            row_ptr[n] = cur[t];
            row_deg[n] = hist[t];
            dinv[n] = rsqrtf(wsum[t] + 1.0f);
        }
    }
    __syncthreads();
    for (int j = g0 + t; j < g1; j += 256) {
        int2 pk = stage[j];
        int r = (pk.x >> 16) & 63;
        int pos = atomicAdd(&cur[r], 1);
        csr4[pos] = (unsigned)(pk.x & 0xFFFF) |
                    ((unsigned)f2b(__int_as_float(pk.y)) << 16);
    }
}

// hp[N,64] = bf16( dinv[r] * (x[N,64] @ W[64,64]) ); 16 rows/block
__global__ __launch_bounds__(256) void gemm_pre_kernel(const float* __restrict__ x,
        const float* __restrict__ W, const float* __restrict__ dinv,
        unsigned short* __restrict__ hp) {
    __shared__ float xs[16][64];
    int t = threadIdx.x;
    int base = blockIdx.x * 16;
    for (int idx = t; idx < 16 * 64; idx += 256)
        xs[idx >> 6][idx & 63] = x[(size_t)(base + (idx >> 6)) * 64 + (idx & 63)];
    __syncthreads();
    int col = t & 63, rq = t >> 6;
    float wc[64];
#pragma unroll
    for (int k = 0; k < 64; ++k) wc[k] = W[k * 64 + col];
    float a0 = 0.f, a1 = 0.f, a2 = 0.f, a3 = 0.f;
#pragma unroll
    for (int k = 0; k < 64; ++k) {
        float wk = wc[k];
        a0 += xs[rq     ][k] * wk;
        a1 += xs[rq +  4][k] * wk;
        a2 += xs[rq +  8][k] * wk;
        a3 += xs[rq + 12][k] * wk;
    }
    int r = base + rq;
    hp[(size_t)(r     ) * 64 + col] = f2b(dinv[r     ] * a0);
    hp[(size_t)(r +  4) * 64 + col] = f2b(dinv[r +  4] * a1);
    hp[(size_t)(r +  8) * 64 + col] = f2b(dinv[r +  8] * a2);
    hp[(size_t)(r + 12) * 64 + col] = f2b(dinv[r + 12] * a3);
}

// gather body (quarter-wave per node): 16 lanes x uint2 = one 128B bf16 row.
// csr read via nontemporal load (streaming, zero reuse) to preserve hp L2 residency.
__device__ __forceinline__ float4 gather_row(int n, int fq, int qbase,
        const int* __restrict__ row_ptr, const int* __restrict__ row_deg,
        const unsigned* __restrict__ csr4, const uint2* __restrict__ hp64) {
    int s0 = row_ptr[n];
    int s1 = s0 + row_deg[n];
    uint2 self = hp64[(size_t)n * 16 + fq];
    float ax = blo(self.x), ay = bhi(self.x), az = blo(self.y), aw = bhi(self.y);
    float bx = 0.f, by = 0.f, bz = 0.f, bw = 0.f;
    for (int base = s0; base < s1; base += 16) {
        int j = base + fq;
        unsigned meta = 0u;      // src=0, w=+0.0 -> contributes nothing
        if (j < s1) meta = __builtin_nontemporal_load(&csr4[j]);
        int m = s1 - base; if (m > 16) m = 16;
        int jj = 0;
        for (; jj + 4 <= m; jj += 4) {
            unsigned m0 = __shfl(meta, qbase + jj + 0);
            unsigned m1 = __shfl(meta, qbase + jj + 1);
            unsigned m2 = __shfl(meta, qbase + jj + 2);
            unsigned m3 = __shfl(meta, qbase + jj + 3);
            uint2 u0 = hp64[(size_t)(m0 & 0xFFFFu) * 16 + fq];
            uint2 u1 = hp64[(size_t)(m1 & 0xFFFFu) * 16 + fq];
            uint2 u2 = hp64[(size_t)(m2 & 0xFFFFu) * 16 + fq];
            uint2 u3 = hp64[(size_t)(m3 & 0xFFFFu) * 16 + fq];
            float w0 = __uint_as_float(m0 & 0xFFFF0000u);
            float w1 = __uint_as_float(m1 & 0xFFFF0000u);
            float w2 = __uint_as_float(m2 & 0xFFFF0000u);
            float w3 = __uint_as_float(m3 & 0xFFFF0000u);
            ax += w0 * blo(u0.x); ay += w0 * bhi(u0.x); az += w0 * blo(u0.y); aw += w0 * bhi(u0.y);
            bx += w1 * blo(u1.x); by += w1 * bhi(u1.x); bz += w1 * blo(u1.y); bw += w1 * bhi(u1.y);
            ax += w2 * blo(u2.x); ay += w2 * bhi(u2.x); az += w2 * blo(u2.y); aw += w2 * bhi(u2.y);
            bx += w3 * blo(u3.x); by += w3 * bhi(u3.x); bz += w3 * blo(u3.y); bw += w3 * bhi(u3.y);
        }
        for (; jj < m; ++jj) {
            unsigned mm = __shfl(meta, qbase + jj);
            uint2 u0 = hp64[(size_t)(mm & 0xFFFFu) * 16 + fq];
            float w0 = __uint_as_float(mm & 0xFFFF0000u);
            ax += w0 * blo(u0.x); ay += w0 * bhi(u0.x); az += w0 * blo(u0.y); aw += w0 * bhi(u0.y);
        }
    }
    return make_float4(ax + bx, ay + by, az + bz, aw + bw);
}

// fused: gather(hp_cur, bias_l) -> y = relu(...) -> hp_next = bf16(dinv * (y @ Wn))
__global__ __launch_bounds__(256) void fused_kernel(const int* __restrict__ row_ptr,
        const int* __restrict__ row_deg, const unsigned* __restrict__ csr4,
        const float* __restrict__ dinv, const uint2* __restrict__ hp_cur,
        const float* __restrict__ bias, const float* __restrict__ Wn,
        unsigned short* __restrict__ hp_next) {
    __shared__ float ys[16][64];
    int t = threadIdx.x;
    int lane = t & 63, q = lane >> 4, fq = lane & 15;
    int ni = ((t >> 6) << 2) + q;
    int n = blockIdx.x * 16 + ni;
    float4 g = gather_row(n, fq, q << 4, row_ptr, row_deg, csr4, hp_cur);
    float dv = dinv[n];
    float4 bb = ((const float4*)bias)[fq];
    float4 y;
    y.x = fmaxf(dv * g.x + bb.x, 0.f);
    y.y = fmaxf(dv * g.y + bb.y, 0.f);
    y.z = fmaxf(dv * g.z + bb.z, 0.f);
    y.w = fmaxf(dv * g.w + bb.w, 0.f);
    ((float4*)ys[ni])[fq] = y;
    __syncthreads();
    // gemm: 16x64 y-tile @ W -> hp_next rows of this block (nontemporal: no reuse this kernel)
    int col = lane, rq = t >> 6;
    float wc[64];
#pragma unroll
    for (int k = 0; k < 64; ++k) wc[k] = Wn[k * 64 + col];
    float a0 = 0.f, a1 = 0.f, a2 = 0.f, a3 = 0.f;
#pragma unroll
    for (int k = 0; k < 64; ++k) {
        float wk = wc[k];
        a0 += ys[rq     ][k] * wk;
        a1 += ys[rq +  4][k] * wk;
        a2 += ys[rq +  8][k] * wk;
        a3 += ys[rq + 12][k] * wk;
    }
    int r = blockIdx.x * 16 + rq;
    __builtin_nontemporal_store(f2b(dinv[r     ] * a0), &hp_next[(size_t)(r     ) * 64 + col]);
    __builtin_nontemporal_store(f2b(dinv[r +  4] * a1), &hp_next[(size_t)(r +  4) * 64 + col]);
    __builtin_nontemporal_store(f2b(dinv[r +  8] * a2), &hp_next[(size_t)(r +  8) * 64 + col]);
    __builtin_nontemporal_store(f2b(dinv[r + 12] * a3), &hp_next[(size_t)(r + 12) * 64 + col]);
}

// final layer: gather + bias + relu -> fp32 out (nontemporal native-vector store)
__global__ __launch_bounds__(256) void final_kernel(const int* __restrict__ row_ptr,
        const int* __restrict__ row_deg, const unsigned* __restrict__ csr4,
        const float* __restrict__ dinv, const uint2* __restrict__ hp_cur,
        const float* __restrict__ bias, float* __restrict__ out) {
    int t = threadIdx.x;
    int lane = t & 63, q = lane >> 4, fq = lane & 15;
    int n = blockIdx.x * 16 + ((t >> 6) << 2) + q;
    float4 g = gather_row(n, fq, q << 4, row_ptr, row_deg, csr4, hp_cur);
    float dv = dinv[n];
    float4 bb = ((const float4*)bias)[fq];
    f32x4 r;
    r.x = fmaxf(dv * g.x + bb.x, 0.f);
    r.y = fmaxf(dv * g.y + bb.y, 0.f);
    r.z = fmaxf(dv * g.z + bb.z, 0.f);
    r.w = fmaxf(dv * g.w + bb.w, 0.f);
    __builtin_nontemporal_store(r, &((f32x4*)out)[(size_t)n * 16 + fq]);
}

extern "C" void kernel_launch(void* const* d_in, const int* in_sizes, int n_in,
                              void* d_out, int out_size, void* d_ws, size_t ws_size,
                              hipStream_t stream) {
    const float* x  = (const float*)d_in[0];
    const int*   ei = (const int*)d_in[1];    // int32 [2, NE] flat
    const float* ew = (const float*)d_in[2];
    const float* W0 = (const float*)d_in[3];
    const float* b0 = (const float*)d_in[4];
    const float* W1 = (const float*)d_in[5];
    const float* b1 = (const float*)d_in[6];
    const float* W2 = (const float*)d_in[7];
    const float* b2 = (const float*)d_in[8];
    float*       out = (float*)d_out;

    const int* src = ei;
    const int* dst = ei + NE;

    // workspace layout (8B-aligned arrays first), ~28 MB total
    int2*     stage   = (int2*)d_ws;                     // CAPTOT (9.6 MB)
    unsigned* csr4    = (unsigned*)(stage + CAPTOT);     // CAPTOT (4.8 MB)
    int*      cursor  = (int*)(csr4 + CAPTOT);           // NB
    int*      row_ptr = cursor + NB;                     // NN
    int*      row_deg = row_ptr + NN;                    // NN
    float*    dinv    = (float*)(row_deg + NN);          // NN
    unsigned short* hpA = (unsigned short*)(dinv + NN);  // NN*64 bf16 (6.4 MB)
    unsigned short* hpB = hpA + (size_t)NN * 64;         // NN*64 bf16 (6.4 MB)

    // ---- CSR build (once, shared by all 3 layers) ----
    (void)hipMemsetAsync(cursor, 0, NB * sizeof(int), stream);
    p12<<<NBLK, 256, 0, stream>>>(src, dst, ew, cursor, stage);
    p3_sort<<<NB, 256, 0, stream>>>(stage, cursor, csr4, row_ptr, row_deg, dinv);

    // ---- layer pipeline: gemm0 -> fused(l0->l1) -> fused(l1->l2) -> final ----
    gemm_pre_kernel<<<NN / 16, 256, 0, stream>>>(x, W0, dinv, hpA);
    fused_kernel<<<NN / 16, 256, 0, stream>>>(row_ptr, row_deg, csr4, dinv,
            (const uint2*)hpA, b0, W1, hpB);
    fused_kernel<<<NN / 16, 256, 0, stream>>>(row_ptr, row_deg, csr4, dinv,
            (const uint2*)hpB, b1, W2, hpA);
    final_kernel<<<NN / 16, 256, 0, stream>>>(row_ptr, row_deg, csr4, dinv,
            (const uint2*)hpA, b2, out);
}